// Round 1
// baseline (6835.464 us; speedup 1.0000x reference)
//
#include <hip/hip_runtime.h>

#define DIM 64

// ---------------- zero a float region (grid-stride) ----------------
__global__ void zero_f32(float* __restrict__ p, long n) {
    long i = (long)blockIdx.x * blockDim.x + threadIdx.x;
    long stride = (long)gridDim.x * blockDim.x;
    for (; i < n; i += stride) p[i] = 0.0f;
}

// ---------------- degree histogram over h_list ----------------
__global__ void count_deg(const int* __restrict__ h, float* __restrict__ deg, int E) {
    int i = blockIdx.x * blockDim.x + threadIdx.x;
    if (i < E) atomicAdd(&deg[h[i]], 1.0f);
}

// ---------------- per-edge normalization g = rsqrt(deg[h]*deg[t]) ----------------
__global__ void compute_g(const int* __restrict__ h, const int* __restrict__ t,
                          const float* __restrict__ deg, float* __restrict__ g, int E) {
    int i = blockIdx.x * blockDim.x + threadIdx.x;
    if (i < E) {
        float dh = fmaxf(deg[h[i]], 1.0f);
        float dt = fmaxf(deg[t[i]], 1.0f);
        g[i] = rsqrtf(dh * dt);
    }
}

// ---------------- SpMM layer 1: gather from the two input embedding tables ----------------
// 16 threads per edge, float4 per thread (64 dims).
__global__ void spmm_l1(const int* __restrict__ h, const int* __restrict__ t,
                        const float* __restrict__ g,
                        const float* __restrict__ ue, const float* __restrict__ ie,
                        int n_users, float* __restrict__ x1, int E) {
    long idx = (long)blockIdx.x * blockDim.x + threadIdx.x;
    long total = (long)E * 16;
    if (idx >= total) return;
    int e  = (int)(idx >> 4);
    int k4 = (int)(idx & 15) << 2;
    int tn = t[e], hn = h[e];
    float gv = g[e];
    const float* src = (tn < n_users) ? (ue + (long)tn * DIM)
                                      : (ie + (long)(tn - n_users) * DIM);
    float4 v = *(const float4*)(src + k4);
    float* dst = x1 + (long)hn * DIM + k4;
    atomicAdd(dst + 0, gv * v.x);
    atomicAdd(dst + 1, gv * v.y);
    atomicAdd(dst + 2, gv * v.z);
    atomicAdd(dst + 3, gv * v.w);
}

// ---------------- SpMM layer 2: contiguous x input ----------------
__global__ void spmm_l2(const int* __restrict__ h, const int* __restrict__ t,
                        const float* __restrict__ g,
                        const float* __restrict__ xin, float* __restrict__ xout, int E) {
    long idx = (long)blockIdx.x * blockDim.x + threadIdx.x;
    long total = (long)E * 16;
    if (idx >= total) return;
    int e  = (int)(idx >> 4);
    int k4 = (int)(idx & 15) << 2;
    int tn = t[e], hn = h[e];
    float gv = g[e];
    float4 v = *(const float4*)(xin + (long)tn * DIM + k4);
    float* dst = xout + (long)hn * DIM + k4;
    atomicAdd(dst + 0, gv * v.x);
    atomicAdd(dst + 1, gv * v.y);
    atomicAdd(dst + 2, gv * v.z);
    atomicAdd(dst + 3, gv * v.w);
}

// ---------------- finalize: out=(x0+x1+x2)/3, hyperbolic lift, write [N,129] ----------------
// One 64-lane wave per node; lane k handles dim k.
__global__ void finalize(const float* __restrict__ ue, const float* __restrict__ ie,
                         int n_users,
                         const float* __restrict__ x1, const float* __restrict__ x2,
                         float* __restrict__ out, int N) {
    long gid = (long)blockIdx.x * blockDim.x + threadIdx.x;
    int node = (int)(gid >> 6);
    int lane = threadIdx.x & 63;
    if (node >= N) return;
    const float* src0 = (node < n_users) ? (ue + (long)node * DIM)
                                         : (ie + (long)(node - n_users) * DIM);
    float v = (src0[lane] + x1[(long)node * DIM + lane] + x2[(long)node * DIM + lane])
              * (1.0f / 3.0f);
    // wave-wide sum of squares (64 lanes)
    float ss = v * v;
    #pragma unroll
    for (int off = 1; off < 64; off <<= 1) ss += __shfl_xor(ss, off);
    float theta = fmaxf(sqrtf(ss), 1e-7f);
    float sc = sinhf(theta) / theta;
    float* o = out + (long)node * 129;
    o[lane] = v;                       // out part (cols 0..63)
    if (lane == 0) o[64] = coshf(theta); // time coordinate
    o[65 + lane] = sc * v;             // spatial part (cols 65..128)
}

extern "C" void kernel_launch(void* const* d_in, const int* in_sizes, int n_in,
                              void* d_out, int out_size, void* d_ws, size_t ws_size,
                              hipStream_t stream) {
    const float* ue = (const float*)d_in[0];
    const float* ie = (const float*)d_in[1];
    const int*   hl = (const int*)d_in[2];
    const int*   tl = (const int*)d_in[3];
    float* out = (float*)d_out;

    const int n_users = in_sizes[0] / DIM;
    const int n_items = in_sizes[1] / DIM;
    const int N = n_users + n_items;
    const int E = in_sizes[2];

    // workspace layout (floats): deg[N] | g[E] | x1[N*64] | x2[N*64]
    float* deg = (float*)d_ws;
    float* g   = deg + N;
    float* x1  = g + E;
    float* x2  = x1 + (size_t)N * DIM;

    // 1) zero deg + x1 + x2 (contiguous except g in the middle: do two calls)
    {
        long n_deg = N;
        long n_x   = 2L * N * DIM;
        zero_f32<<<1024, 256, 0, stream>>>(deg, n_deg);
        zero_f32<<<2048, 256, 0, stream>>>(x1, n_x);
    }

    // 2) degree histogram
    count_deg<<<(E + 255) / 256, 256, 0, stream>>>(hl, deg, E);

    // 3) edge weights
    compute_g<<<(E + 255) / 256, 256, 0, stream>>>(hl, tl, deg, g, E);

    // 4) layer 1: x1 = G @ x0 (x0 = concat(ue, ie))
    {
        long total = (long)E * 16;
        int blocks = (int)((total + 255) / 256);
        spmm_l1<<<blocks, 256, 0, stream>>>(hl, tl, g, ue, ie, n_users, x1, E);
    }

    // 5) layer 2: x2 = G @ x1
    {
        long total = (long)E * 16;
        int blocks = (int)((total + 255) / 256);
        spmm_l2<<<blocks, 256, 0, stream>>>(hl, tl, g, x1, x2, E);
    }

    // 6) finalize: out = (x0+x1+x2)/3, expmap0 lift, concat -> [N, 129]
    {
        long total = (long)N * 64;
        int blocks = (int)((total + 255) / 256);
        finalize<<<blocks, 256, 0, stream>>>(ue, ie, n_users, x1, x2, out, N);
    }
}

// Round 2
// 851.828 us; speedup vs baseline: 8.0245x; 8.0245x over previous
//
#include <hip/hip_runtime.h>

#define DIM 64
#define SCAN_ELEMS 1024   // elements per scan block (256 threads x 4)

// ---------------- zero u32 region ----------------
__global__ void zero_u32(unsigned* __restrict__ p, int n) {
    int i = blockIdx.x * blockDim.x + threadIdx.x;
    int stride = gridDim.x * blockDim.x;
    for (; i < n; i += stride) p[i] = 0u;
}

// ---------------- degree histogram over h_list (int atomics) ----------------
__global__ void count_deg(const int* __restrict__ h, unsigned* __restrict__ cnt, int E) {
    int i = blockIdx.x * blockDim.x + threadIdx.x;
    if (i < E) atomicAdd(&cnt[h[i]], 1u);
}

// ---------------- scan step 1: per-block sums over counts ----------------
__global__ void block_reduce_counts(const unsigned* __restrict__ cnt,
                                    unsigned* __restrict__ bsum, int N) {
    __shared__ unsigned s[256];
    int tid = threadIdx.x;
    long base = (long)blockIdx.x * SCAN_ELEMS + tid * 4;
    unsigned sum = 0;
    #pragma unroll
    for (int j = 0; j < 4; ++j) { long i = base + j; if (i < N) sum += cnt[i]; }
    s[tid] = sum; __syncthreads();
    for (int off = 128; off > 0; off >>= 1) {
        if (tid < off) s[tid] += s[tid + off];
        __syncthreads();
    }
    if (tid == 0) bsum[blockIdx.x] = s[0];
}

// ---------------- scan step 2: exclusive scan of block sums (1 block) ----------------
__global__ void scan_block_sums(unsigned* __restrict__ bsum, int nb,
                                unsigned* __restrict__ row_ptr, int N, int E) {
    __shared__ unsigned s[256];
    int tid = threadIdx.x;
    unsigned running = 0;
    for (int base = 0; base < nb; base += 256) {
        int i = base + tid;
        unsigned v = (i < nb) ? bsum[i] : 0u;
        s[tid] = v; __syncthreads();
        for (int off = 1; off < 256; off <<= 1) {
            unsigned t = (tid >= off) ? s[tid - off] : 0u;
            __syncthreads();
            s[tid] += t; __syncthreads();
        }
        unsigned incl = s[tid];
        if (i < nb) bsum[i] = running + (incl - v);   // exclusive
        unsigned total = s[255];
        __syncthreads();
        running += total;
    }
    if (tid == 0) row_ptr[N] = (unsigned)E;
}

// ---------------- scan step 3: intra-block scan -> row_ptr ----------------
__global__ void scan_within_block(const unsigned* __restrict__ cnt,
                                  const unsigned* __restrict__ bsum,
                                  unsigned* __restrict__ row_ptr, int N) {
    __shared__ unsigned s[256];
    int tid = threadIdx.x;
    long base = (long)blockIdx.x * SCAN_ELEMS + tid * 4;
    unsigned c[4]; unsigned lsum = 0;
    #pragma unroll
    for (int j = 0; j < 4; ++j) {
        c[j] = (base + j < N) ? cnt[base + j] : 0u;
        lsum += c[j];
    }
    s[tid] = lsum; __syncthreads();
    for (int off = 1; off < 256; off <<= 1) {
        unsigned t = (tid >= off) ? s[tid - off] : 0u;
        __syncthreads();
        s[tid] += t; __syncthreads();
    }
    unsigned off = bsum[blockIdx.x] + (s[tid] - lsum);
    #pragma unroll
    for (int j = 0; j < 4; ++j) {
        if (base + j < N) { row_ptr[base + j] = off; off += c[j]; }
    }
}

// ---------------- bucket edges into CSR, computing w on the fly ----------------
__global__ void bucket_edges(const int* __restrict__ h, const int* __restrict__ t,
                             const unsigned* __restrict__ rp,
                             unsigned* __restrict__ cursor,
                             int* __restrict__ col, float* __restrict__ w, int E) {
    int i = blockIdx.x * blockDim.x + threadIdx.x;
    if (i >= E) return;
    int hn = h[i], tn = t[i];
    unsigned pos = atomicAdd(&cursor[hn], 1u);
    float dh = fmaxf((float)(rp[hn + 1] - rp[hn]), 1.0f);
    float dt = fmaxf((float)(rp[tn + 1] - rp[tn]), 1.0f);
    col[pos] = tn;
    w[pos] = rsqrtf(dh * dt);
}

// ---------------- pull SpMM layer 1: x1 = G @ concat(ue, ie) ----------------
// One 64-lane wave per row; lane = dim. Coalesced 256B row gathers, no atomics.
__global__ void spmm_pull_l1(const unsigned* __restrict__ rp,
                             const int* __restrict__ col, const float* __restrict__ w,
                             const float* __restrict__ ue, const float* __restrict__ ie,
                             int n_users, float* __restrict__ x1, int N) {
    int node = blockIdx.x * (blockDim.x >> 6) + (threadIdx.x >> 6);
    int lane = threadIdx.x & 63;
    if (node >= N) return;
    int e0 = (int)rp[node], e1 = (int)rp[node + 1];
    float acc = 0.0f;
    int e = e0;
    for (; e + 4 <= e1; e += 4) {
        int c0 = col[e], c1 = col[e + 1], c2 = col[e + 2], c3 = col[e + 3];
        float w0 = w[e], w1 = w[e + 1], w2 = w[e + 2], w3 = w[e + 3];
        const float* s0 = (c0 < n_users) ? ue + (long)c0 * DIM : ie + (long)(c0 - n_users) * DIM;
        const float* s1 = (c1 < n_users) ? ue + (long)c1 * DIM : ie + (long)(c1 - n_users) * DIM;
        const float* s2 = (c2 < n_users) ? ue + (long)c2 * DIM : ie + (long)(c2 - n_users) * DIM;
        const float* s3 = (c3 < n_users) ? ue + (long)c3 * DIM : ie + (long)(c3 - n_users) * DIM;
        float v0 = s0[lane], v1 = s1[lane], v2 = s2[lane], v3 = s3[lane];
        acc += w0 * v0 + w1 * v1 + w2 * v2 + w3 * v3;
    }
    for (; e < e1; ++e) {
        int c = col[e]; float wv = w[e];
        const float* s = (c < n_users) ? ue + (long)c * DIM : ie + (long)(c - n_users) * DIM;
        acc += wv * s[lane];
    }
    x1[(long)node * DIM + lane] = acc;
}

// ---------------- pull SpMM layer 2 fused with finalize ----------------
// x2-row lives in registers; out = (x0+x1+x2)/3, hyperbolic lift, write [N,129].
__global__ void spmm_l2_finalize(const unsigned* __restrict__ rp,
                                 const int* __restrict__ col, const float* __restrict__ w,
                                 const float* __restrict__ ue, const float* __restrict__ ie,
                                 int n_users, const float* __restrict__ x1,
                                 float* __restrict__ out, int N) {
    int node = blockIdx.x * (blockDim.x >> 6) + (threadIdx.x >> 6);
    int lane = threadIdx.x & 63;
    if (node >= N) return;
    int e0 = (int)rp[node], e1 = (int)rp[node + 1];
    float acc = 0.0f;
    int e = e0;
    for (; e + 4 <= e1; e += 4) {
        int c0 = col[e], c1 = col[e + 1], c2 = col[e + 2], c3 = col[e + 3];
        float w0 = w[e], w1 = w[e + 1], w2 = w[e + 2], w3 = w[e + 3];
        float v0 = x1[(long)c0 * DIM + lane];
        float v1 = x1[(long)c1 * DIM + lane];
        float v2 = x1[(long)c2 * DIM + lane];
        float v3 = x1[(long)c3 * DIM + lane];
        acc += w0 * v0 + w1 * v1 + w2 * v2 + w3 * v3;
    }
    for (; e < e1; ++e) {
        acc += w[e] * x1[(long)col[e] * DIM + lane];
    }
    const float* src0 = (node < n_users) ? ue + (long)node * DIM
                                         : ie + (long)(node - n_users) * DIM;
    float v = (src0[lane] + x1[(long)node * DIM + lane] + acc) * (1.0f / 3.0f);
    float ss = v * v;
    #pragma unroll
    for (int off = 1; off < 64; off <<= 1) ss += __shfl_xor(ss, off);
    float theta = fmaxf(sqrtf(ss), 1e-7f);
    float sc = sinhf(theta) / theta;
    float* o = out + (long)node * 129;
    o[lane] = v;
    if (lane == 0) o[64] = coshf(theta);
    o[65 + lane] = sc * v;
}

extern "C" void kernel_launch(void* const* d_in, const int* in_sizes, int n_in,
                              void* d_out, int out_size, void* d_ws, size_t ws_size,
                              hipStream_t stream) {
    const float* ue = (const float*)d_in[0];
    const float* ie = (const float*)d_in[1];
    const int*   hl = (const int*)d_in[2];
    const int*   tl = (const int*)d_in[3];
    float* out = (float*)d_out;

    const int n_users = in_sizes[0] / DIM;
    const int n_items = in_sizes[1] / DIM;
    const int N = n_users + n_items;
    const int E = in_sizes[2];
    const int nblocks_scan = (N + SCAN_ELEMS - 1) / SCAN_ELEMS;

    // workspace layout (256B-aligned regions):
    // counts[N] | row_ptr[N+1] | cursor[N] | bsum[nblocks] | col[E] | w[E] | x1[N*64]
    auto align = [](size_t x) { return (x + 255) & ~(size_t)255; };
    char* p = (char*)d_ws;
    unsigned* counts  = (unsigned*)p;            p += align((size_t)N * 4);
    unsigned* row_ptr = (unsigned*)p;            p += align((size_t)(N + 1) * 4);
    unsigned* cursor  = (unsigned*)p;            p += align((size_t)N * 4);
    unsigned* bsum    = (unsigned*)p;            p += align((size_t)nblocks_scan * 4);
    int*      col     = (int*)p;                 p += align((size_t)E * 4);
    float*    w       = (float*)p;               p += align((size_t)E * 4);
    float*    x1      = (float*)p;               // N*64 floats

    // 1) zero counts
    zero_u32<<<256, 256, 0, stream>>>(counts, N);

    // 2) degree histogram
    count_deg<<<(E + 255) / 256, 256, 0, stream>>>(hl, counts, E);

    // 3) exclusive scan counts -> row_ptr
    block_reduce_counts<<<nblocks_scan, 256, 0, stream>>>(counts, bsum, N);
    scan_block_sums<<<1, 256, 0, stream>>>(bsum, nblocks_scan, row_ptr, N, E);
    scan_within_block<<<nblocks_scan, 256, 0, stream>>>(counts, bsum, row_ptr, N);

    // 4) cursor = row_ptr[0..N)
    hipMemcpyAsync(cursor, row_ptr, (size_t)N * 4, hipMemcpyDeviceToDevice, stream);

    // 5) bucket edges into CSR (col, w)
    bucket_edges<<<(E + 255) / 256, 256, 0, stream>>>(hl, tl, row_ptr, cursor, col, w, E);

    // 6) layer 1: x1 = G @ x0 (pull, no atomics)
    {
        int rows_per_block = 256 / 64;
        int blocks = (N + rows_per_block - 1) / rows_per_block;
        spmm_pull_l1<<<blocks, 256, 0, stream>>>(row_ptr, col, w, ue, ie, n_users, x1, N);
    }

    // 7) layer 2 + finalize fused
    {
        int rows_per_block = 256 / 64;
        int blocks = (N + rows_per_block - 1) / rows_per_block;
        spmm_l2_finalize<<<blocks, 256, 0, stream>>>(row_ptr, col, w, ue, ie, n_users,
                                                     x1, out, N);
    }
}

// Round 3
// 822.245 us; speedup vs baseline: 8.3132x; 1.0360x over previous
//
#include <hip/hip_runtime.h>

#define DIM 64
#define SCAN_ELEMS 1024   // elements per scan block (256 threads x 4)

// ---------------- zero u32 region ----------------
__global__ void zero_u32(unsigned* __restrict__ p, int n) {
    int i = blockIdx.x * blockDim.x + threadIdx.x;
    int stride = gridDim.x * blockDim.x;
    for (; i < n; i += stride) p[i] = 0u;
}

// ---------------- degree histogram over h_list (int atomics) ----------------
__global__ void count_deg(const int* __restrict__ h, unsigned* __restrict__ cnt, int E) {
    int i = blockIdx.x * blockDim.x + threadIdx.x;
    if (i < E) atomicAdd(&cnt[h[i]], 1u);
}

// ---------------- scan step 1: per-block sums over counts ----------------
__global__ void block_reduce_counts(const unsigned* __restrict__ cnt,
                                    unsigned* __restrict__ bsum, int N) {
    __shared__ unsigned s[256];
    int tid = threadIdx.x;
    long base = (long)blockIdx.x * SCAN_ELEMS + tid * 4;
    unsigned sum = 0;
    #pragma unroll
    for (int j = 0; j < 4; ++j) { long i = base + j; if (i < N) sum += cnt[i]; }
    s[tid] = sum; __syncthreads();
    for (int off = 128; off > 0; off >>= 1) {
        if (tid < off) s[tid] += s[tid + off];
        __syncthreads();
    }
    if (tid == 0) bsum[blockIdx.x] = s[0];
}

// ---------------- scan step 2: exclusive scan of block sums (1 block) ----------------
__global__ void scan_block_sums(unsigned* __restrict__ bsum, int nb,
                                unsigned* __restrict__ row_ptr, int N, int E) {
    __shared__ unsigned s[256];
    int tid = threadIdx.x;
    unsigned running = 0;
    for (int base = 0; base < nb; base += 256) {
        int i = base + tid;
        unsigned v = (i < nb) ? bsum[i] : 0u;
        s[tid] = v; __syncthreads();
        for (int off = 1; off < 256; off <<= 1) {
            unsigned t = (tid >= off) ? s[tid - off] : 0u;
            __syncthreads();
            s[tid] += t; __syncthreads();
        }
        unsigned incl = s[tid];
        if (i < nb) bsum[i] = running + (incl - v);   // exclusive
        unsigned total = s[255];
        __syncthreads();
        running += total;
    }
    if (tid == 0) row_ptr[N] = (unsigned)E;
}

// ---------------- scan step 3: intra-block scan -> row_ptr (+ fused rdeg) ----------------
__global__ void scan_within_block(const unsigned* __restrict__ cnt,
                                  const unsigned* __restrict__ bsum,
                                  unsigned* __restrict__ row_ptr,
                                  float* __restrict__ rdeg, int N) {
    __shared__ unsigned s[256];
    int tid = threadIdx.x;
    long base = (long)blockIdx.x * SCAN_ELEMS + tid * 4;
    unsigned c[4]; unsigned lsum = 0;
    #pragma unroll
    for (int j = 0; j < 4; ++j) {
        c[j] = (base + j < N) ? cnt[base + j] : 0u;
        lsum += c[j];
    }
    s[tid] = lsum; __syncthreads();
    for (int off = 1; off < 256; off <<= 1) {
        unsigned t = (tid >= off) ? s[tid - off] : 0u;
        __syncthreads();
        s[tid] += t; __syncthreads();
    }
    unsigned off = bsum[blockIdx.x] + (s[tid] - lsum);
    #pragma unroll
    for (int j = 0; j < 4; ++j) {
        if (base + j < N) {
            row_ptr[base + j] = off;
            rdeg[base + j] = rsqrtf(fmaxf((float)c[j], 1.0f));
            off += c[j];
        }
    }
}

// ---------------- bucket edges into CSR (col only; weights factored out) ----------------
__global__ void bucket_edges(const int* __restrict__ h, const int* __restrict__ t,
                             unsigned* __restrict__ cursor,
                             int* __restrict__ col, int E) {
    int i = blockIdx.x * blockDim.x + threadIdx.x;
    if (i >= E) return;
    int hn = h[i], tn = t[i];
    unsigned pos = atomicAdd(&cursor[hn], 1u);
    col[pos] = tn;
}

// ---------------- pull SpMM layer 1: x1 = G @ concat(ue, ie) ----------------
// One 64-lane wave per row; lane = dim. acc = rdeg[h] * sum(rdeg[t] * x0[t]).
__global__ void spmm_pull_l1(const unsigned* __restrict__ rp,
                             const int* __restrict__ col,
                             const float* __restrict__ rdeg,
                             const float* __restrict__ ue, const float* __restrict__ ie,
                             int n_users, float* __restrict__ x1, int N) {
    int node = blockIdx.x * (blockDim.x >> 6) + (threadIdx.x >> 6);
    int lane = threadIdx.x & 63;
    if (node >= N) return;
    int e0 = __builtin_amdgcn_readfirstlane((int)rp[node]);
    int e1 = __builtin_amdgcn_readfirstlane((int)rp[node + 1]);
    float acc = 0.0f;
    int e = e0;
    for (; e + 8 <= e1; e += 8) {
        float part = 0.0f;
        #pragma unroll
        for (int j = 0; j < 8; ++j) {
            int c = col[e + j];
            float wv = rdeg[c];
            const float* s = (c < n_users) ? ue + (long)c * DIM
                                           : ie + (long)(c - n_users) * DIM;
            part += wv * s[lane];
        }
        acc += part;
    }
    for (; e < e1; ++e) {
        int c = col[e];
        const float* s = (c < n_users) ? ue + (long)c * DIM
                                       : ie + (long)(c - n_users) * DIM;
        acc += rdeg[c] * s[lane];
    }
    x1[(long)node * DIM + lane] = rdeg[node] * acc;
}

// ---------------- pull SpMM layer 2 fused with finalize ----------------
__global__ void spmm_l2_finalize(const unsigned* __restrict__ rp,
                                 const int* __restrict__ col,
                                 const float* __restrict__ rdeg,
                                 const float* __restrict__ ue, const float* __restrict__ ie,
                                 int n_users, const float* __restrict__ x1,
                                 float* __restrict__ out, int N) {
    int node = blockIdx.x * (blockDim.x >> 6) + (threadIdx.x >> 6);
    int lane = threadIdx.x & 63;
    if (node >= N) return;
    int e0 = __builtin_amdgcn_readfirstlane((int)rp[node]);
    int e1 = __builtin_amdgcn_readfirstlane((int)rp[node + 1]);
    float acc = 0.0f;
    int e = e0;
    for (; e + 8 <= e1; e += 8) {
        float part = 0.0f;
        #pragma unroll
        for (int j = 0; j < 8; ++j) {
            int c = col[e + j];
            part += rdeg[c] * x1[(long)c * DIM + lane];
        }
        acc += part;
    }
    for (; e < e1; ++e) {
        int c = col[e];
        acc += rdeg[c] * x1[(long)c * DIM + lane];
    }
    acc *= rdeg[node];
    const float* src0 = (node < n_users) ? ue + (long)node * DIM
                                         : ie + (long)(node - n_users) * DIM;
    float v = (src0[lane] + x1[(long)node * DIM + lane] + acc) * (1.0f / 3.0f);
    float ss = v * v;
    #pragma unroll
    for (int off = 1; off < 64; off <<= 1) ss += __shfl_xor(ss, off);
    float theta = fmaxf(sqrtf(ss), 1e-7f);
    float sc = sinhf(theta) / theta;
    float* o = out + (long)node * 129;
    o[lane] = v;
    if (lane == 0) o[64] = coshf(theta);
    o[65 + lane] = sc * v;
}

extern "C" void kernel_launch(void* const* d_in, const int* in_sizes, int n_in,
                              void* d_out, int out_size, void* d_ws, size_t ws_size,
                              hipStream_t stream) {
    const float* ue = (const float*)d_in[0];
    const float* ie = (const float*)d_in[1];
    const int*   hl = (const int*)d_in[2];
    const int*   tl = (const int*)d_in[3];
    float* out = (float*)d_out;

    const int n_users = in_sizes[0] / DIM;
    const int n_items = in_sizes[1] / DIM;
    const int N = n_users + n_items;
    const int E = in_sizes[2];
    const int nblocks_scan = (N + SCAN_ELEMS - 1) / SCAN_ELEMS;

    // workspace layout (256B-aligned regions):
    // counts[N] | row_ptr[N+1] | cursor[N] | bsum[nb] | rdeg[N] | col[E] | x1[N*64]
    auto align = [](size_t x) { return (x + 255) & ~(size_t)255; };
    char* p = (char*)d_ws;
    unsigned* counts  = (unsigned*)p;            p += align((size_t)N * 4);
    unsigned* row_ptr = (unsigned*)p;            p += align((size_t)(N + 1) * 4);
    unsigned* cursor  = (unsigned*)p;            p += align((size_t)N * 4);
    unsigned* bsum    = (unsigned*)p;            p += align((size_t)nblocks_scan * 4);
    float*    rdeg    = (float*)p;               p += align((size_t)N * 4);
    int*      col     = (int*)p;                 p += align((size_t)E * 4);
    float*    x1      = (float*)p;               // N*64 floats

    // 1) zero counts
    zero_u32<<<256, 256, 0, stream>>>(counts, N);

    // 2) degree histogram
    count_deg<<<(E + 255) / 256, 256, 0, stream>>>(hl, counts, E);

    // 3) exclusive scan counts -> row_ptr (+ rdeg fused)
    block_reduce_counts<<<nblocks_scan, 256, 0, stream>>>(counts, bsum, N);
    scan_block_sums<<<1, 256, 0, stream>>>(bsum, nblocks_scan, row_ptr, N, E);
    scan_within_block<<<nblocks_scan, 256, 0, stream>>>(counts, bsum, row_ptr, rdeg, N);

    // 4) cursor = row_ptr[0..N)
    hipMemcpyAsync(cursor, row_ptr, (size_t)N * 4, hipMemcpyDeviceToDevice, stream);

    // 5) bucket edges into CSR (col only)
    bucket_edges<<<(E + 255) / 256, 256, 0, stream>>>(hl, tl, cursor, col, E);

    // 6) layer 1: x1 = G @ x0 (pull, no atomics)
    {
        int rows_per_block = 256 / 64;
        int blocks = (N + rows_per_block - 1) / rows_per_block;
        spmm_pull_l1<<<blocks, 256, 0, stream>>>(row_ptr, col, rdeg, ue, ie, n_users, x1, N);
    }

    // 7) layer 2 + finalize fused
    {
        int rows_per_block = 256 / 64;
        int blocks = (N + rows_per_block - 1) / rows_per_block;
        spmm_l2_finalize<<<blocks, 256, 0, stream>>>(row_ptr, col, rdeg, ue, ie, n_users,
                                                     x1, out, N);
    }
}

// Round 4
// 763.532 us; speedup vs baseline: 8.9524x; 1.0769x over previous
//
#include <hip/hip_runtime.h>

#define DIM 64
#define SCAN_ELEMS 1024   // elements per scan block (256 threads x 4)
#define CHUNK 16384       // edges per partition block
#define BSHIFT 11         // 2048 nodes per coarse bucket
#define MAXB 128          // max coarse buckets (N<=262144)

// ---------------- zero u32 region ----------------
__global__ void zero_u32(unsigned* __restrict__ p, int n) {
    int i = blockIdx.x * blockDim.x + threadIdx.x;
    int stride = gridDim.x * blockDim.x;
    for (; i < n; i += stride) p[i] = 0u;
}

// ---------------- degree histogram over h_list (int atomics) ----------------
__global__ void count_deg(const int* __restrict__ h, unsigned* __restrict__ cnt, int E) {
    int i = blockIdx.x * blockDim.x + threadIdx.x;
    if (i < E) atomicAdd(&cnt[h[i]], 1u);
}

// ---------------- scan step 1: per-block sums over counts ----------------
__global__ void block_reduce_counts(const unsigned* __restrict__ cnt,
                                    unsigned* __restrict__ bsum, int N) {
    __shared__ unsigned s[256];
    int tid = threadIdx.x;
    long base = (long)blockIdx.x * SCAN_ELEMS + tid * 4;
    unsigned sum = 0;
    #pragma unroll
    for (int j = 0; j < 4; ++j) { long i = base + j; if (i < N) sum += cnt[i]; }
    s[tid] = sum; __syncthreads();
    for (int off = 128; off > 0; off >>= 1) {
        if (tid < off) s[tid] += s[tid + off];
        __syncthreads();
    }
    if (tid == 0) bsum[blockIdx.x] = s[0];
}

// ---------------- scan step 2: exclusive scan of block sums (1 block) ----------------
__global__ void scan_block_sums(unsigned* __restrict__ bsum, int nb,
                                unsigned* __restrict__ row_ptr, int N, int E) {
    __shared__ unsigned s[256];
    int tid = threadIdx.x;
    unsigned running = 0;
    for (int base = 0; base < nb; base += 256) {
        int i = base + tid;
        unsigned v = (i < nb) ? bsum[i] : 0u;
        s[tid] = v; __syncthreads();
        for (int off = 1; off < 256; off <<= 1) {
            unsigned t = (tid >= off) ? s[tid - off] : 0u;
            __syncthreads();
            s[tid] += t; __syncthreads();
        }
        unsigned incl = s[tid];
        if (i < nb) bsum[i] = running + (incl - v);   // exclusive
        unsigned total = s[255];
        __syncthreads();
        running += total;
    }
    if (tid == 0) row_ptr[N] = (unsigned)E;
}

// ---------------- scan step 3: intra-block scan -> row_ptr (+ fused rdeg) ----------------
__global__ void scan_within_block(const unsigned* __restrict__ cnt,
                                  const unsigned* __restrict__ bsum,
                                  unsigned* __restrict__ row_ptr,
                                  float* __restrict__ rdeg, int N) {
    __shared__ unsigned s[256];
    int tid = threadIdx.x;
    long base = (long)blockIdx.x * SCAN_ELEMS + tid * 4;
    unsigned c[4]; unsigned lsum = 0;
    #pragma unroll
    for (int j = 0; j < 4; ++j) {
        c[j] = (base + j < N) ? cnt[base + j] : 0u;
        lsum += c[j];
    }
    s[tid] = lsum; __syncthreads();
    for (int off = 1; off < 256; off <<= 1) {
        unsigned t = (tid >= off) ? s[tid - off] : 0u;
        __syncthreads();
        s[tid] += t; __syncthreads();
    }
    unsigned off = bsum[blockIdx.x] + (s[tid] - lsum);
    #pragma unroll
    for (int j = 0; j < 4; ++j) {
        if (base + j < N) {
            row_ptr[base + j] = off;
            rdeg[base + j] = rsqrtf(fmaxf((float)c[j], 1.0f));
            off += c[j];
        }
    }
}

// ---------------- init coarse-bucket cursors: bcur[b] = rp[min(b<<BSHIFT, N)] ----------------
__global__ void init_bcur(const unsigned* __restrict__ rp, unsigned* __restrict__ bcur,
                          int nb, int N) {
    int i = blockIdx.x * blockDim.x + threadIdx.x;
    if (i < nb) {
        long node = (long)i << BSHIFT;
        if (node > N) node = N;
        bcur[i] = rp[node];
    }
}

// ---------------- coarse partition: (h,t) pairs -> bucket-contiguous tmp ----------------
// Per-block LDS histogram + one chunk reservation per (block,bucket) keeps
// writes to tmp in ~1KB sequential runs -> full-line L2 evictions.
__global__ void partition_edges(const int* __restrict__ h, const int* __restrict__ t,
                                unsigned* __restrict__ bcur, int2* __restrict__ tmp,
                                int E, int nb) {
    __shared__ unsigned cnt[MAXB];
    int tid = threadIdx.x;
    long start = (long)blockIdx.x * CHUNK;
    long end = start + CHUNK; if (end > E) end = E;
    for (int i = tid; i < nb; i += blockDim.x) cnt[i] = 0u;
    __syncthreads();
    for (long i = start + tid; i < end; i += blockDim.x)
        atomicAdd(&cnt[((unsigned)h[i]) >> BSHIFT], 1u);
    __syncthreads();
    for (int i = tid; i < nb; i += blockDim.x) {
        unsigned c = cnt[i];
        cnt[i] = c ? atomicAdd(&bcur[i], c) : 0u;   // reserve chunk; cnt becomes cursor
    }
    __syncthreads();
    for (long i = start + tid; i < end; i += blockDim.x) {
        int hn = h[i], tn = t[i];
        unsigned pos = atomicAdd(&cnt[((unsigned)hn) >> BSHIFT], 1u);
        tmp[pos] = make_int2(hn, tn);
    }
}

// ---------------- fine scatter: bucket-partitioned pairs -> exact CSR position ----------------
// Consecutive threads hit an ~8KB cursor window and ~128KB col window (L2-local).
__global__ void scatter_csr(const int2* __restrict__ tmp, unsigned* __restrict__ cursor,
                            int* __restrict__ col, int E) {
    int i = blockIdx.x * blockDim.x + threadIdx.x;
    if (i >= E) return;
    int2 e = tmp[i];
    unsigned pos = atomicAdd(&cursor[e.x], 1u);
    col[pos] = e.y;
}

// ---------------- pull SpMM layer 1: x1 = G @ concat(ue, ie) ----------------
__global__ void spmm_pull_l1(const unsigned* __restrict__ rp,
                             const int* __restrict__ col,
                             const float* __restrict__ rdeg,
                             const float* __restrict__ ue, const float* __restrict__ ie,
                             int n_users, float* __restrict__ x1, int N) {
    int node = blockIdx.x * (blockDim.x >> 6) + (threadIdx.x >> 6);
    int lane = threadIdx.x & 63;
    if (node >= N) return;
    int e0 = __builtin_amdgcn_readfirstlane((int)rp[node]);
    int e1 = __builtin_amdgcn_readfirstlane((int)rp[node + 1]);
    float acc = 0.0f;
    int e = e0;
    for (; e + 8 <= e1; e += 8) {
        float part = 0.0f;
        #pragma unroll
        for (int j = 0; j < 8; ++j) {
            int c = col[e + j];
            float wv = rdeg[c];
            const float* s = (c < n_users) ? ue + (long)c * DIM
                                           : ie + (long)(c - n_users) * DIM;
            part += wv * s[lane];
        }
        acc += part;
    }
    for (; e < e1; ++e) {
        int c = col[e];
        const float* s = (c < n_users) ? ue + (long)c * DIM
                                       : ie + (long)(c - n_users) * DIM;
        acc += rdeg[c] * s[lane];
    }
    x1[(long)node * DIM + lane] = rdeg[node] * acc;
}

// ---------------- pull SpMM layer 2 fused with finalize ----------------
__global__ void spmm_l2_finalize(const unsigned* __restrict__ rp,
                                 const int* __restrict__ col,
                                 const float* __restrict__ rdeg,
                                 const float* __restrict__ ue, const float* __restrict__ ie,
                                 int n_users, const float* __restrict__ x1,
                                 float* __restrict__ out, int N) {
    int node = blockIdx.x * (blockDim.x >> 6) + (threadIdx.x >> 6);
    int lane = threadIdx.x & 63;
    if (node >= N) return;
    int e0 = __builtin_amdgcn_readfirstlane((int)rp[node]);
    int e1 = __builtin_amdgcn_readfirstlane((int)rp[node + 1]);
    float acc = 0.0f;
    int e = e0;
    for (; e + 8 <= e1; e += 8) {
        float part = 0.0f;
        #pragma unroll
        for (int j = 0; j < 8; ++j) {
            int c = col[e + j];
            part += rdeg[c] * x1[(long)c * DIM + lane];
        }
        acc += part;
    }
    for (; e < e1; ++e) {
        int c = col[e];
        acc += rdeg[c] * x1[(long)c * DIM + lane];
    }
    acc *= rdeg[node];
    const float* src0 = (node < n_users) ? ue + (long)node * DIM
                                         : ie + (long)(node - n_users) * DIM;
    float v = (src0[lane] + x1[(long)node * DIM + lane] + acc) * (1.0f / 3.0f);
    float ss = v * v;
    #pragma unroll
    for (int off = 1; off < 64; off <<= 1) ss += __shfl_xor(ss, off);
    float theta = fmaxf(sqrtf(ss), 1e-7f);
    float sc = sinhf(theta) / theta;
    float* o = out + (long)node * 129;
    o[lane] = v;
    if (lane == 0) o[64] = coshf(theta);
    o[65 + lane] = sc * v;
}

extern "C" void kernel_launch(void* const* d_in, const int* in_sizes, int n_in,
                              void* d_out, int out_size, void* d_ws, size_t ws_size,
                              hipStream_t stream) {
    const float* ue = (const float*)d_in[0];
    const float* ie = (const float*)d_in[1];
    const int*   hl = (const int*)d_in[2];
    const int*   tl = (const int*)d_in[3];
    float* out = (float*)d_out;

    const int n_users = in_sizes[0] / DIM;
    const int n_items = in_sizes[1] / DIM;
    const int N = n_users + n_items;
    const int E = in_sizes[2];
    const int nblocks_scan = (N + SCAN_ELEMS - 1) / SCAN_ELEMS;
    const int nb = (N + (1 << BSHIFT) - 1) >> BSHIFT;   // coarse buckets (<=MAXB)

    // workspace layout (256B-aligned):
    // counts[N] | row_ptr[N+1] | cursor[N] | bsum | bcur[nb] | rdeg[N] | col[E] | tmp[E int2] | x1[N*64]
    auto align = [](size_t x) { return (x + 255) & ~(size_t)255; };
    char* p = (char*)d_ws;
    unsigned* counts  = (unsigned*)p;            p += align((size_t)N * 4);
    unsigned* row_ptr = (unsigned*)p;            p += align((size_t)(N + 1) * 4);
    unsigned* cursor  = (unsigned*)p;            p += align((size_t)N * 4);
    unsigned* bsum    = (unsigned*)p;            p += align((size_t)nblocks_scan * 4);
    unsigned* bcur    = (unsigned*)p;            p += align((size_t)MAXB * 4);
    float*    rdeg    = (float*)p;               p += align((size_t)N * 4);
    int*      col     = (int*)p;                 p += align((size_t)E * 4);
    int2*     tmp     = (int2*)p;                p += align((size_t)E * 8);
    float*    x1      = (float*)p;               // N*64 floats

    // 1) zero counts
    zero_u32<<<256, 256, 0, stream>>>(counts, N);

    // 2) degree histogram
    count_deg<<<(E + 255) / 256, 256, 0, stream>>>(hl, counts, E);

    // 3) exclusive scan counts -> row_ptr (+ rdeg fused)
    block_reduce_counts<<<nblocks_scan, 256, 0, stream>>>(counts, bsum, N);
    scan_block_sums<<<1, 256, 0, stream>>>(bsum, nblocks_scan, row_ptr, N, E);
    scan_within_block<<<nblocks_scan, 256, 0, stream>>>(counts, bsum, row_ptr, rdeg, N);

    // 4) cursor = row_ptr[0..N); bcur = rp at bucket starts
    hipMemcpyAsync(cursor, row_ptr, (size_t)N * 4, hipMemcpyDeviceToDevice, stream);
    init_bcur<<<1, 256, 0, stream>>>(row_ptr, bcur, nb, N);

    // 5) coarse partition of (h,t) by h>>BSHIFT into tmp (CSR-shared index space)
    {
        int blocks = (E + CHUNK - 1) / CHUNK;
        partition_edges<<<blocks, 256, 0, stream>>>(hl, tl, bcur, tmp, E, nb);
    }

    // 6) fine scatter into CSR col (L2-local cursor + col windows)
    scatter_csr<<<(E + 255) / 256, 256, 0, stream>>>(tmp, cursor, col, E);

    // 7) layer 1: x1 = G @ x0 (pull, no atomics)
    {
        int rows_per_block = 256 / 64;
        int blocks = (N + rows_per_block - 1) / rows_per_block;
        spmm_pull_l1<<<blocks, 256, 0, stream>>>(row_ptr, col, rdeg, ue, ie, n_users, x1, N);
    }

    // 8) layer 2 + finalize fused
    {
        int rows_per_block = 256 / 64;
        int blocks = (N + rows_per_block - 1) / rows_per_block;
        spmm_l2_finalize<<<blocks, 256, 0, stream>>>(row_ptr, col, rdeg, ue, ie, n_users,
                                                     x1, out, N);
    }
}

// Round 5
// 723.015 us; speedup vs baseline: 9.4541x; 1.0560x over previous
//
#include <hip/hip_runtime.h>

#define DIM 64
#define SCAN_ELEMS 1024   // elements per scan block (256 threads x 4)
#define CHUNK 16384       // edges per partition block
#define BSHIFT 11         // 2048 nodes per coarse bucket
#define MAXB 128          // max coarse buckets (N<=262144)

// ---- bf16 helpers (RNE) ----
__device__ __forceinline__ unsigned short f2bf(float f) {
    unsigned u = __float_as_uint(f);
    unsigned r = (u + 0x7FFFu + ((u >> 16) & 1u)) >> 16;
    return (unsigned short)r;
}
__device__ __forceinline__ float bf2f(unsigned short h) {
    return __uint_as_float(((unsigned)h) << 16);
}

// ---------------- zero u32 region ----------------
__global__ void zero_u32(unsigned* __restrict__ p, int n) {
    int i = blockIdx.x * blockDim.x + threadIdx.x;
    int stride = gridDim.x * blockDim.x;
    for (; i < n; i += stride) p[i] = 0u;
}

// ---------------- degree histogram over h_list (int atomics) ----------------
__global__ void count_deg(const int* __restrict__ h, unsigned* __restrict__ cnt, int E) {
    int i = blockIdx.x * blockDim.x + threadIdx.x;
    if (i < E) atomicAdd(&cnt[h[i]], 1u);
}

// ---------------- convert concat(ue,ie) f32 -> bf16 table ----------------
__global__ void cvt_x0(const float* __restrict__ ue, const float* __restrict__ ie,
                       long nu_elems, unsigned short* __restrict__ x0h, long M) {
    long i4 = ((long)blockIdx.x * blockDim.x + threadIdx.x) * 4;
    long stride = (long)gridDim.x * blockDim.x * 4;
    for (; i4 < M; i4 += stride) {
        const float* src = (i4 < nu_elems) ? ue + i4 : ie + (i4 - nu_elems);
        float4 v = *(const float4*)src;
        ushort4 o;
        o.x = f2bf(v.x); o.y = f2bf(v.y); o.z = f2bf(v.z); o.w = f2bf(v.w);
        *(ushort4*)(x0h + i4) = o;
    }
}

// ---------------- scan step 1: per-block sums over counts ----------------
__global__ void block_reduce_counts(const unsigned* __restrict__ cnt,
                                    unsigned* __restrict__ bsum, int N) {
    __shared__ unsigned s[256];
    int tid = threadIdx.x;
    long base = (long)blockIdx.x * SCAN_ELEMS + tid * 4;
    unsigned sum = 0;
    #pragma unroll
    for (int j = 0; j < 4; ++j) { long i = base + j; if (i < N) sum += cnt[i]; }
    s[tid] = sum; __syncthreads();
    for (int off = 128; off > 0; off >>= 1) {
        if (tid < off) s[tid] += s[tid + off];
        __syncthreads();
    }
    if (tid == 0) bsum[blockIdx.x] = s[0];
}

// ---------------- scan step 2: exclusive scan of block sums (1 block) ----------------
__global__ void scan_block_sums(unsigned* __restrict__ bsum, int nb,
                                unsigned* __restrict__ row_ptr, int N, int E) {
    __shared__ unsigned s[256];
    int tid = threadIdx.x;
    unsigned running = 0;
    for (int base = 0; base < nb; base += 256) {
        int i = base + tid;
        unsigned v = (i < nb) ? bsum[i] : 0u;
        s[tid] = v; __syncthreads();
        for (int off = 1; off < 256; off <<= 1) {
            unsigned t = (tid >= off) ? s[tid - off] : 0u;
            __syncthreads();
            s[tid] += t; __syncthreads();
        }
        unsigned incl = s[tid];
        if (i < nb) bsum[i] = running + (incl - v);   // exclusive
        unsigned total = s[255];
        __syncthreads();
        running += total;
    }
    if (tid == 0) row_ptr[N] = (unsigned)E;
}

// ---------------- scan step 3: intra-block scan -> row_ptr (+ fused rdeg) ----------------
__global__ void scan_within_block(const unsigned* __restrict__ cnt,
                                  const unsigned* __restrict__ bsum,
                                  unsigned* __restrict__ row_ptr,
                                  float* __restrict__ rdeg, int N) {
    __shared__ unsigned s[256];
    int tid = threadIdx.x;
    long base = (long)blockIdx.x * SCAN_ELEMS + tid * 4;
    unsigned c[4]; unsigned lsum = 0;
    #pragma unroll
    for (int j = 0; j < 4; ++j) {
        c[j] = (base + j < N) ? cnt[base + j] : 0u;
        lsum += c[j];
    }
    s[tid] = lsum; __syncthreads();
    for (int off = 1; off < 256; off <<= 1) {
        unsigned t = (tid >= off) ? s[tid - off] : 0u;
        __syncthreads();
        s[tid] += t; __syncthreads();
    }
    unsigned off = bsum[blockIdx.x] + (s[tid] - lsum);
    #pragma unroll
    for (int j = 0; j < 4; ++j) {
        if (base + j < N) {
            row_ptr[base + j] = off;
            rdeg[base + j] = rsqrtf(fmaxf((float)c[j], 1.0f));
            off += c[j];
        }
    }
}

// ---------------- init coarse-bucket cursors: bcur[b] = rp[min(b<<BSHIFT, N)] ----------------
__global__ void init_bcur(const unsigned* __restrict__ rp, unsigned* __restrict__ bcur,
                          int nb, int N) {
    int i = blockIdx.x * blockDim.x + threadIdx.x;
    if (i < nb) {
        long node = (long)i << BSHIFT;
        if (node > N) node = N;
        bcur[i] = rp[node];
    }
}

// ---------------- coarse partition: (h,t) pairs -> bucket-contiguous tmp ----------------
__global__ void partition_edges(const int* __restrict__ h, const int* __restrict__ t,
                                unsigned* __restrict__ bcur, int2* __restrict__ tmp,
                                int E, int nb) {
    __shared__ unsigned cnt[MAXB];
    int tid = threadIdx.x;
    long start = (long)blockIdx.x * CHUNK;
    long end = start + CHUNK; if (end > E) end = E;
    for (int i = tid; i < nb; i += blockDim.x) cnt[i] = 0u;
    __syncthreads();
    for (long i = start + tid; i < end; i += blockDim.x)
        atomicAdd(&cnt[((unsigned)h[i]) >> BSHIFT], 1u);
    __syncthreads();
    for (int i = tid; i < nb; i += blockDim.x) {
        unsigned c = cnt[i];
        cnt[i] = c ? atomicAdd(&bcur[i], c) : 0u;   // reserve chunk; cnt becomes cursor
    }
    __syncthreads();
    for (long i = start + tid; i < end; i += blockDim.x) {
        int hn = h[i], tn = t[i];
        unsigned pos = atomicAdd(&cnt[((unsigned)hn) >> BSHIFT], 1u);
        tmp[pos] = make_int2(hn, tn);
    }
}

// ---------------- fine scatter: bucket-partitioned pairs -> exact CSR position ----------------
__global__ void scatter_csr(const int2* __restrict__ tmp, unsigned* __restrict__ cursor,
                            int* __restrict__ col, int E) {
    int i = blockIdx.x * blockDim.x + threadIdx.x;
    if (i >= E) return;
    int2 e = tmp[i];
    unsigned pos = atomicAdd(&cursor[e.x], 1u);
    col[pos] = e.y;
}

// ---------------- pull SpMM layer 1: x1h = G @ x0h (bf16 gathers, f32 accum) ----------------
__global__ void spmm_pull_l1(const unsigned* __restrict__ rp,
                             const int* __restrict__ col,
                             const float* __restrict__ rdeg,
                             const unsigned short* __restrict__ x0h,
                             unsigned short* __restrict__ x1h, int N) {
    int node = blockIdx.x * (blockDim.x >> 6) + (threadIdx.x >> 6);
    int lane = threadIdx.x & 63;
    if (node >= N) return;
    int e0 = __builtin_amdgcn_readfirstlane((int)rp[node]);
    int e1 = __builtin_amdgcn_readfirstlane((int)rp[node + 1]);
    float acc = 0.0f;
    int e = e0;
    for (; e + 8 <= e1; e += 8) {
        float part = 0.0f;
        #pragma unroll
        for (int j = 0; j < 8; ++j) {
            int c = col[e + j];
            part += rdeg[c] * bf2f(x0h[((size_t)c << 6) + lane]);
        }
        acc += part;
    }
    for (; e < e1; ++e) {
        int c = col[e];
        acc += rdeg[c] * bf2f(x0h[((size_t)c << 6) + lane]);
    }
    x1h[((size_t)node << 6) + lane] = f2bf(rdeg[node] * acc);
}

// ---------------- pull SpMM layer 2 fused with finalize ----------------
__global__ void spmm_l2_finalize(const unsigned* __restrict__ rp,
                                 const int* __restrict__ col,
                                 const float* __restrict__ rdeg,
                                 const float* __restrict__ ue, const float* __restrict__ ie,
                                 int n_users, const unsigned short* __restrict__ x1h,
                                 float* __restrict__ out, int N) {
    int node = blockIdx.x * (blockDim.x >> 6) + (threadIdx.x >> 6);
    int lane = threadIdx.x & 63;
    if (node >= N) return;
    int e0 = __builtin_amdgcn_readfirstlane((int)rp[node]);
    int e1 = __builtin_amdgcn_readfirstlane((int)rp[node + 1]);
    float acc = 0.0f;
    int e = e0;
    for (; e + 8 <= e1; e += 8) {
        float part = 0.0f;
        #pragma unroll
        for (int j = 0; j < 8; ++j) {
            int c = col[e + j];
            part += rdeg[c] * bf2f(x1h[((size_t)c << 6) + lane]);
        }
        acc += part;
    }
    for (; e < e1; ++e) {
        int c = col[e];
        acc += rdeg[c] * bf2f(x1h[((size_t)c << 6) + lane]);
    }
    acc *= rdeg[node];
    const float* src0 = (node < n_users) ? ue + (long)node * DIM
                                         : ie + (long)(node - n_users) * DIM;
    float x1v = bf2f(x1h[((size_t)node << 6) + lane]);
    float v = (src0[lane] + x1v + acc) * (1.0f / 3.0f);
    float ss = v * v;
    #pragma unroll
    for (int off = 1; off < 64; off <<= 1) ss += __shfl_xor(ss, off);
    float theta = fmaxf(sqrtf(ss), 1e-7f);
    float sc = sinhf(theta) / theta;
    float* o = out + (long)node * 129;
    o[lane] = v;
    if (lane == 0) o[64] = coshf(theta);
    o[65 + lane] = sc * v;
}

extern "C" void kernel_launch(void* const* d_in, const int* in_sizes, int n_in,
                              void* d_out, int out_size, void* d_ws, size_t ws_size,
                              hipStream_t stream) {
    const float* ue = (const float*)d_in[0];
    const float* ie = (const float*)d_in[1];
    const int*   hl = (const int*)d_in[2];
    const int*   tl = (const int*)d_in[3];
    float* out = (float*)d_out;

    const int n_users = in_sizes[0] / DIM;
    const int n_items = in_sizes[1] / DIM;
    const int N = n_users + n_items;
    const int E = in_sizes[2];
    const int nblocks_scan = (N + SCAN_ELEMS - 1) / SCAN_ELEMS;
    const int nb = (N + (1 << BSHIFT) - 1) >> BSHIFT;   // coarse buckets (<=MAXB)
    const long M = (long)N * DIM;

    // workspace layout (256B-aligned):
    // counts[N] | row_ptr[N+1] | cursor[N] | bsum | bcur | rdeg[N] | col[E]
    //   | tmp[E int2] | x0h[N*64 u16] | x1h[N*64 u16]
    auto align = [](size_t x) { return (x + 255) & ~(size_t)255; };
    char* p = (char*)d_ws;
    unsigned* counts  = (unsigned*)p;            p += align((size_t)N * 4);
    unsigned* row_ptr = (unsigned*)p;            p += align((size_t)(N + 1) * 4);
    unsigned* cursor  = (unsigned*)p;            p += align((size_t)N * 4);
    unsigned* bsum    = (unsigned*)p;            p += align((size_t)nblocks_scan * 4);
    unsigned* bcur    = (unsigned*)p;            p += align((size_t)MAXB * 4);
    float*    rdeg    = (float*)p;               p += align((size_t)N * 4);
    int*      col     = (int*)p;                 p += align((size_t)E * 4);
    int2*     tmp     = (int2*)p;                p += align((size_t)E * 8);
    unsigned short* x0h = (unsigned short*)p;    p += align((size_t)M * 2);
    unsigned short* x1h = (unsigned short*)p;    // M u16

    // 1) zero counts
    zero_u32<<<256, 256, 0, stream>>>(counts, N);

    // 2) degree histogram
    count_deg<<<(E + 255) / 256, 256, 0, stream>>>(hl, counts, E);

    // 2b) convert x0 -> bf16 table (independent of CSR build)
    {
        long threads = (M + 3) / 4;
        int blocks = (int)((threads + 255) / 256);
        cvt_x0<<<blocks, 256, 0, stream>>>(ue, ie, (long)n_users * DIM, x0h, M);
    }

    // 3) exclusive scan counts -> row_ptr (+ rdeg fused)
    block_reduce_counts<<<nblocks_scan, 256, 0, stream>>>(counts, bsum, N);
    scan_block_sums<<<1, 256, 0, stream>>>(bsum, nblocks_scan, row_ptr, N, E);
    scan_within_block<<<nblocks_scan, 256, 0, stream>>>(counts, bsum, row_ptr, rdeg, N);

    // 4) cursor = row_ptr[0..N); bcur = rp at bucket starts
    hipMemcpyAsync(cursor, row_ptr, (size_t)N * 4, hipMemcpyDeviceToDevice, stream);
    init_bcur<<<1, 256, 0, stream>>>(row_ptr, bcur, nb, N);

    // 5) coarse partition of (h,t) by h>>BSHIFT into tmp (CSR-shared index space)
    {
        int blocks = (E + CHUNK - 1) / CHUNK;
        partition_edges<<<blocks, 256, 0, stream>>>(hl, tl, bcur, tmp, E, nb);
    }

    // 6) fine scatter into CSR col (L2-local cursor + col windows)
    scatter_csr<<<(E + 255) / 256, 256, 0, stream>>>(tmp, cursor, col, E);

    // 7) layer 1: x1h = G @ x0h (pull, bf16 gathers)
    {
        int rows_per_block = 256 / 64;
        int blocks = (N + rows_per_block - 1) / rows_per_block;
        spmm_pull_l1<<<blocks, 256, 0, stream>>>(row_ptr, col, rdeg, x0h, x1h, N);
    }

    // 8) layer 2 + finalize fused
    {
        int rows_per_block = 256 / 64;
        int blocks = (N + rows_per_block - 1) / rows_per_block;
        spmm_l2_finalize<<<blocks, 256, 0, stream>>>(row_ptr, col, rdeg, ue, ie, n_users,
                                                     x1h, out, N);
    }
}

// Round 6
// 697.260 us; speedup vs baseline: 9.8033x; 1.0369x over previous
//
#include <hip/hip_runtime.h>

#define DIM 64
#define SCAN_ELEMS 1024   // elements per scan block (256 threads x 4)
#define CHUNK 16384       // edges per partition block
#define BSHIFT 11         // 2048 nodes per coarse bucket
#define MAXB 128          // max coarse buckets (N<=262144)

// ---- bf16 helpers (RNE) ----
__device__ __forceinline__ unsigned f2bf(float f) {
    unsigned u = __float_as_uint(f);
    return (u + 0x7FFFu + ((u >> 16) & 1u)) >> 16;
}
__device__ __forceinline__ float bflo(unsigned u) {   // low u16 -> f32
    return __uint_as_float(u << 16);
}
__device__ __forceinline__ float bfhi(unsigned u) {   // high u16 -> f32
    return __uint_as_float(u & 0xFFFF0000u);
}

// ---------------- zero u32 region ----------------
__global__ void zero_u32(unsigned* __restrict__ p, int n) {
    int i = blockIdx.x * blockDim.x + threadIdx.x;
    int stride = gridDim.x * blockDim.x;
    for (; i < n; i += stride) p[i] = 0u;
}

// ---------------- degree histogram over h_list (int atomics) ----------------
__global__ void count_deg(const int* __restrict__ h, unsigned* __restrict__ cnt, int E) {
    int i = blockIdx.x * blockDim.x + threadIdx.x;
    if (i < E) atomicAdd(&cnt[h[i]], 1u);
}

// ---------------- convert concat(ue,ie) f32 -> bf16 table ----------------
__global__ void cvt_x0(const float* __restrict__ ue, const float* __restrict__ ie,
                       long nu_elems, unsigned short* __restrict__ x0h, long M) {
    long i4 = ((long)blockIdx.x * blockDim.x + threadIdx.x) * 4;
    long stride = (long)gridDim.x * blockDim.x * 4;
    for (; i4 < M; i4 += stride) {
        const float* src = (i4 < nu_elems) ? ue + i4 : ie + (i4 - nu_elems);
        float4 v = *(const float4*)src;
        ushort4 o;
        o.x = (unsigned short)f2bf(v.x); o.y = (unsigned short)f2bf(v.y);
        o.z = (unsigned short)f2bf(v.z); o.w = (unsigned short)f2bf(v.w);
        *(ushort4*)(x0h + i4) = o;
    }
}

// ---------------- scan step 1: per-block sums over counts ----------------
__global__ void block_reduce_counts(const unsigned* __restrict__ cnt,
                                    unsigned* __restrict__ bsum, int N) {
    __shared__ unsigned s[256];
    int tid = threadIdx.x;
    long base = (long)blockIdx.x * SCAN_ELEMS + tid * 4;
    unsigned sum = 0;
    #pragma unroll
    for (int j = 0; j < 4; ++j) { long i = base + j; if (i < N) sum += cnt[i]; }
    s[tid] = sum; __syncthreads();
    for (int off = 128; off > 0; off >>= 1) {
        if (tid < off) s[tid] += s[tid + off];
        __syncthreads();
    }
    if (tid == 0) bsum[blockIdx.x] = s[0];
}

// ---------------- scan step 2: exclusive scan of block sums (1 block) ----------------
__global__ void scan_block_sums(unsigned* __restrict__ bsum, int nb,
                                unsigned* __restrict__ row_ptr, int N, int E) {
    __shared__ unsigned s[256];
    int tid = threadIdx.x;
    unsigned running = 0;
    for (int base = 0; base < nb; base += 256) {
        int i = base + tid;
        unsigned v = (i < nb) ? bsum[i] : 0u;
        s[tid] = v; __syncthreads();
        for (int off = 1; off < 256; off <<= 1) {
            unsigned t = (tid >= off) ? s[tid - off] : 0u;
            __syncthreads();
            s[tid] += t; __syncthreads();
        }
        unsigned incl = s[tid];
        if (i < nb) bsum[i] = running + (incl - v);   // exclusive
        unsigned total = s[255];
        __syncthreads();
        running += total;
    }
    if (tid == 0) row_ptr[N] = (unsigned)E;
}

// ---------------- scan step 3: intra-block scan -> row_ptr (+ fused rdeg) ----------------
__global__ void scan_within_block(const unsigned* __restrict__ cnt,
                                  const unsigned* __restrict__ bsum,
                                  unsigned* __restrict__ row_ptr,
                                  float* __restrict__ rdeg, int N) {
    __shared__ unsigned s[256];
    int tid = threadIdx.x;
    long base = (long)blockIdx.x * SCAN_ELEMS + tid * 4;
    unsigned c[4]; unsigned lsum = 0;
    #pragma unroll
    for (int j = 0; j < 4; ++j) {
        c[j] = (base + j < N) ? cnt[base + j] : 0u;
        lsum += c[j];
    }
    s[tid] = lsum; __syncthreads();
    for (int off = 1; off < 256; off <<= 1) {
        unsigned t = (tid >= off) ? s[tid - off] : 0u;
        __syncthreads();
        s[tid] += t; __syncthreads();
    }
    unsigned off = bsum[blockIdx.x] + (s[tid] - lsum);
    #pragma unroll
    for (int j = 0; j < 4; ++j) {
        if (base + j < N) {
            row_ptr[base + j] = off;
            rdeg[base + j] = rsqrtf(fmaxf((float)c[j], 1.0f));
            off += c[j];
        }
    }
}

// ---------------- init coarse-bucket cursors: bcur[b] = rp[min(b<<BSHIFT, N)] ----------------
__global__ void init_bcur(const unsigned* __restrict__ rp, unsigned* __restrict__ bcur,
                          int nb, int N) {
    int i = blockIdx.x * blockDim.x + threadIdx.x;
    if (i < nb) {
        long node = (long)i << BSHIFT;
        if (node > N) node = N;
        bcur[i] = rp[node];
    }
}

// ---------------- coarse partition: (h,t) pairs -> bucket-contiguous tmp ----------------
__global__ void partition_edges(const int* __restrict__ h, const int* __restrict__ t,
                                unsigned* __restrict__ bcur, int2* __restrict__ tmp,
                                int E, int nb) {
    __shared__ unsigned cnt[MAXB];
    int tid = threadIdx.x;
    long start = (long)blockIdx.x * CHUNK;
    long end = start + CHUNK; if (end > E) end = E;
    for (int i = tid; i < nb; i += blockDim.x) cnt[i] = 0u;
    __syncthreads();
    for (long i = start + tid; i < end; i += blockDim.x)
        atomicAdd(&cnt[((unsigned)h[i]) >> BSHIFT], 1u);
    __syncthreads();
    for (int i = tid; i < nb; i += blockDim.x) {
        unsigned c = cnt[i];
        cnt[i] = c ? atomicAdd(&bcur[i], c) : 0u;   // reserve chunk; cnt becomes cursor
    }
    __syncthreads();
    for (long i = start + tid; i < end; i += blockDim.x) {
        int hn = h[i], tn = t[i];
        unsigned pos = atomicAdd(&cnt[((unsigned)hn) >> BSHIFT], 1u);
        tmp[pos] = make_int2(hn, tn);
    }
}

// ---------------- fine scatter: bucket-partitioned pairs -> exact CSR position ----------------
__global__ void scatter_csr(const int2* __restrict__ tmp, unsigned* __restrict__ cursor,
                            int* __restrict__ col, int E) {
    int i = blockIdx.x * blockDim.x + threadIdx.x;
    if (i >= E) return;
    int2 e = tmp[i];
    unsigned pos = atomicAdd(&cursor[e.x], 1u);
    col[pos] = e.y;
}

// ---------------- pull SpMM layer 1: x1w = G @ x0w ----------------
// Two edges per wave: lanes 0-31 edge e, lanes 32-63 edge e+1; each lane
// loads one u32 (2 bf16 dims). Halves VMEM instrs + address VALU per edge.
__global__ void spmm_pull_l1(const unsigned* __restrict__ rp,
                             const int* __restrict__ col,
                             const float* __restrict__ rdeg,
                             const unsigned* __restrict__ x0w,
                             unsigned* __restrict__ x1w, int N) {
    int node = blockIdx.x * (blockDim.x >> 6) + (threadIdx.x >> 6);
    int lane = threadIdx.x & 63;
    int half = lane >> 5;
    int hl   = lane & 31;
    if (node >= N) return;
    int e0 = __builtin_amdgcn_readfirstlane((int)rp[node]);
    int e1 = __builtin_amdgcn_readfirstlane((int)rp[node + 1]);
    float accx = 0.0f, accy = 0.0f;
    int e = e0;
    for (; e + 8 <= e1; e += 8) {
        #pragma unroll
        for (int j = 0; j < 4; ++j) {
            int c = col[e + 2 * j + half];
            float wv = rdeg[c];
            unsigned u = x0w[((size_t)c << 5) + hl];
            accx += wv * bflo(u);
            accy += wv * bfhi(u);
        }
    }
    for (; e + 2 <= e1; e += 2) {
        int c = col[e + half];
        float wv = rdeg[c];
        unsigned u = x0w[((size_t)c << 5) + hl];
        accx += wv * bflo(u);
        accy += wv * bfhi(u);
    }
    if (e < e1 && half == 0) {   // odd tail edge: half A only
        int c = col[e];
        float wv = rdeg[c];
        unsigned u = x0w[((size_t)c << 5) + hl];
        accx += wv * bflo(u);
        accy += wv * bfhi(u);
    }
    accx += __shfl_xor(accx, 32);
    accy += __shfl_xor(accy, 32);
    if (half == 0) {
        float rd = rdeg[node];
        unsigned lo = f2bf(rd * accx);
        unsigned hi = f2bf(rd * accy);
        x1w[((size_t)node << 5) + hl] = (hi << 16) | lo;
    }
}

// ---------------- pull SpMM layer 2 fused with finalize ----------------
__global__ void spmm_l2_finalize(const unsigned* __restrict__ rp,
                                 const int* __restrict__ col,
                                 const float* __restrict__ rdeg,
                                 const unsigned* __restrict__ x0w,
                                 const unsigned* __restrict__ x1w,
                                 float* __restrict__ out, int N) {
    int node = blockIdx.x * (blockDim.x >> 6) + (threadIdx.x >> 6);
    int lane = threadIdx.x & 63;
    int half = lane >> 5;
    int hl   = lane & 31;
    if (node >= N) return;
    int e0 = __builtin_amdgcn_readfirstlane((int)rp[node]);
    int e1 = __builtin_amdgcn_readfirstlane((int)rp[node + 1]);
    float accx = 0.0f, accy = 0.0f;
    int e = e0;
    for (; e + 8 <= e1; e += 8) {
        #pragma unroll
        for (int j = 0; j < 4; ++j) {
            int c = col[e + 2 * j + half];
            float wv = rdeg[c];
            unsigned u = x1w[((size_t)c << 5) + hl];
            accx += wv * bflo(u);
            accy += wv * bfhi(u);
        }
    }
    for (; e + 2 <= e1; e += 2) {
        int c = col[e + half];
        float wv = rdeg[c];
        unsigned u = x1w[((size_t)c << 5) + hl];
        accx += wv * bflo(u);
        accy += wv * bfhi(u);
    }
    if (e < e1 && half == 0) {
        int c = col[e];
        float wv = rdeg[c];
        unsigned u = x1w[((size_t)c << 5) + hl];
        accx += wv * bflo(u);
        accy += wv * bfhi(u);
    }
    accx += __shfl_xor(accx, 32);
    accy += __shfl_xor(accy, 32);
    float rd = rdeg[node];
    accx *= rd; accy *= rd;
    // self rows (both halves load identical values; broadcast)
    unsigned u0 = x0w[((size_t)node << 5) + hl];
    unsigned u1 = x1w[((size_t)node << 5) + hl];
    float vx = (bflo(u0) + bflo(u1) + accx) * (1.0f / 3.0f);
    float vy = (bfhi(u0) + bfhi(u1) + accy) * (1.0f / 3.0f);
    // sum of squares over the 32-lane half (halves are duplicates)
    float ss = vx * vx + vy * vy;
    #pragma unroll
    for (int off = 1; off < 32; off <<= 1) ss += __shfl_xor(ss, off);
    float theta = fmaxf(sqrtf(ss), 1e-7f);
    float sc = sinhf(theta) / theta;
    float* o = out + (long)node * 129;
    if (half == 0) {
        float2 v2 = make_float2(vx, vy);
        *(float2*)(o + 2 * hl) = v2;            // dims 0..63 (8B-aligned)
        if (hl == 0) o[64] = coshf(theta);      // time coordinate
    } else {
        o[65 + 2 * hl] = sc * vx;               // lifted spatial part
        o[66 + 2 * hl] = sc * vy;
    }
}

extern "C" void kernel_launch(void* const* d_in, const int* in_sizes, int n_in,
                              void* d_out, int out_size, void* d_ws, size_t ws_size,
                              hipStream_t stream) {
    const float* ue = (const float*)d_in[0];
    const float* ie = (const float*)d_in[1];
    const int*   hl = (const int*)d_in[2];
    const int*   tl = (const int*)d_in[3];
    float* out = (float*)d_out;

    const int n_users = in_sizes[0] / DIM;
    const int n_items = in_sizes[1] / DIM;
    const int N = n_users + n_items;
    const int E = in_sizes[2];
    const int nblocks_scan = (N + SCAN_ELEMS - 1) / SCAN_ELEMS;
    const int nb = (N + (1 << BSHIFT) - 1) >> BSHIFT;   // coarse buckets (<=MAXB)
    const long M = (long)N * DIM;

    // workspace layout (256B-aligned):
    // counts[N] | row_ptr[N+1] | cursor[N] | bsum | bcur | rdeg[N] | col[E]
    //   | tmp[E int2] | x0h[M u16] | x1h[M u16]
    auto align = [](size_t x) { return (x + 255) & ~(size_t)255; };
    char* p = (char*)d_ws;
    unsigned* counts  = (unsigned*)p;            p += align((size_t)N * 4);
    unsigned* row_ptr = (unsigned*)p;            p += align((size_t)(N + 1) * 4);
    unsigned* cursor  = (unsigned*)p;            p += align((size_t)N * 4);
    unsigned* bsum    = (unsigned*)p;            p += align((size_t)nblocks_scan * 4);
    unsigned* bcur    = (unsigned*)p;            p += align((size_t)MAXB * 4);
    float*    rdeg    = (float*)p;               p += align((size_t)N * 4);
    int*      col     = (int*)p;                 p += align((size_t)E * 4);
    int2*     tmp     = (int2*)p;                p += align((size_t)E * 8);
    unsigned short* x0h = (unsigned short*)p;    p += align((size_t)M * 2);
    unsigned short* x1h = (unsigned short*)p;    // M u16
    const unsigned* x0w = (const unsigned*)x0h;
    unsigned* x1w = (unsigned*)x1h;

    // 1) zero counts
    zero_u32<<<256, 256, 0, stream>>>(counts, N);

    // 2) degree histogram
    count_deg<<<(E + 255) / 256, 256, 0, stream>>>(hl, counts, E);

    // 2b) convert x0 -> bf16 table (independent of CSR build)
    {
        long threads = (M + 3) / 4;
        int blocks = (int)((threads + 255) / 256);
        cvt_x0<<<blocks, 256, 0, stream>>>(ue, ie, (long)n_users * DIM, x0h, M);
    }

    // 3) exclusive scan counts -> row_ptr (+ rdeg fused)
    block_reduce_counts<<<nblocks_scan, 256, 0, stream>>>(counts, bsum, N);
    scan_block_sums<<<1, 256, 0, stream>>>(bsum, nblocks_scan, row_ptr, N, E);
    scan_within_block<<<nblocks_scan, 256, 0, stream>>>(counts, bsum, row_ptr, rdeg, N);

    // 4) cursor = row_ptr[0..N); bcur = rp at bucket starts
    hipMemcpyAsync(cursor, row_ptr, (size_t)N * 4, hipMemcpyDeviceToDevice, stream);
    init_bcur<<<1, 256, 0, stream>>>(row_ptr, bcur, nb, N);

    // 5) coarse partition of (h,t) by h>>BSHIFT into tmp (CSR-shared index space)
    {
        int blocks = (E + CHUNK - 1) / CHUNK;
        partition_edges<<<blocks, 256, 0, stream>>>(hl, tl, bcur, tmp, E, nb);
    }

    // 6) fine scatter into CSR col (L2-local cursor + col windows)
    scatter_csr<<<(E + 255) / 256, 256, 0, stream>>>(tmp, cursor, col, E);

    // 7) layer 1: x1 = G @ x0 (pull, 2 edges/wave, u32 bf16x2 gathers)
    {
        int rows_per_block = 256 / 64;
        int blocks = (N + rows_per_block - 1) / rows_per_block;
        spmm_pull_l1<<<blocks, 256, 0, stream>>>(row_ptr, col, rdeg, x0w, x1w, N);
    }

    // 8) layer 2 + finalize fused
    {
        int rows_per_block = 256 / 64;
        int blocks = (N + rows_per_block - 1) / rows_per_block;
        spmm_l2_finalize<<<blocks, 256, 0, stream>>>(row_ptr, col, rdeg, x0w, x1w,
                                                     out, N);
    }
}